// Round 3
// baseline (347.619 us; speedup 1.0000x reference)
//
#include <hip/hip_runtime.h>

#define N_NODES 50000
#define N_EDGES_MAX 800000
#define D_IN    128
#define D_OUT   64

// ---------------- Phase 1: support = x @ W  (f32 vector FMA) ----------------
#define NPB 16

__global__ __launch_bounds__(256) void gemm_xw(
    const float* __restrict__ x, const float* __restrict__ W,
    float* __restrict__ support) {
  __shared__ float Wlds[D_IN][D_OUT];   // 32 KiB
  __shared__ float xlds[NPB][D_IN];     //  8 KiB
  const int tid = threadIdx.x;
  const int node0 = blockIdx.x * NPB;

  const float4* W4 = (const float4*)W;
  float4* Wl4 = (float4*)Wlds;
#pragma unroll
  for (int i = 0; i < (D_IN * D_OUT / 4) / 256; ++i)
    Wl4[tid + i * 256] = W4[tid + i * 256];

  const float4* x4 = (const float4*)(x + (size_t)node0 * D_IN);
  float4* xl4 = (float4*)xlds;
#pragma unroll
  for (int i = 0; i < (NPB * D_IN / 4) / 256; ++i)
    xl4[tid + i * 256] = x4[tid + i * 256];

  __syncthreads();

  const int f = tid & 63;
  const int g = tid >> 6;
  float acc0 = 0.f, acc1 = 0.f, acc2 = 0.f, acc3 = 0.f;

#pragma unroll
  for (int k = 0; k < D_IN; k += 4) {
    const float w0 = Wlds[k + 0][f];
    const float w1 = Wlds[k + 1][f];
    const float w2 = Wlds[k + 2][f];
    const float w3 = Wlds[k + 3][f];
    const float4 xa = *(const float4*)&xlds[g * 4 + 0][k];
    const float4 xb = *(const float4*)&xlds[g * 4 + 1][k];
    const float4 xc = *(const float4*)&xlds[g * 4 + 2][k];
    const float4 xd = *(const float4*)&xlds[g * 4 + 3][k];
    acc0 += xa.x * w0 + xa.y * w1 + xa.z * w2 + xa.w * w3;
    acc1 += xb.x * w0 + xb.y * w1 + xb.z * w2 + xb.w * w3;
    acc2 += xc.x * w0 + xc.y * w1 + xc.z * w2 + xc.w * w3;
    acc3 += xd.x * w0 + xd.y * w1 + xd.z * w2 + xd.w * w3;
  }

  const int nbase = node0 + g * 4;
  support[(size_t)(nbase + 0) * D_OUT + f] = acc0;
  support[(size_t)(nbase + 1) * D_OUT + f] = acc1;
  support[(size_t)(nbase + 2) * D_OUT + f] = acc2;
  support[(size_t)(nbase + 3) * D_OUT + f] = acc3;
}

// ---------------- Phase 2a: histogram of edge_dst ---------------------------
__global__ __launch_bounds__(256) void hist_dst(
    const int* __restrict__ edst, int* __restrict__ counts, int n_edges) {
  int i = (blockIdx.x * 256 + threadIdx.x) * 4;
  if (i + 3 < n_edges) {
    const int4 d = *(const int4*)(edst + i);
    atomicAdd(&counts[d.x], 1);
    atomicAdd(&counts[d.y], 1);
    atomicAdd(&counts[d.z], 1);
    atomicAdd(&counts[d.w], 1);
  } else {
    for (; i < n_edges; ++i) atomicAdd(&counts[edst[i]], 1);
  }
}

// ---------------- Phase 2b: exclusive scan (single block, 1024 thr) ---------
__global__ __launch_bounds__(1024) void scan_offsets(
    const int* __restrict__ counts, int* __restrict__ offsets,
    int* __restrict__ cursor) {
  __shared__ int tsum[1024];
  const int t = threadIdx.x;
  const int PER = (N_NODES + 1023) / 1024;  // 49
  const int beg = t * PER;
  const int end = min(beg + PER, N_NODES);
  int s = 0;
  for (int i = beg; i < end; ++i) s += counts[i];
  tsum[t] = s;
  __syncthreads();
  // inclusive Hillis-Steele scan of per-thread sums
  for (int off = 1; off < 1024; off <<= 1) {
    const int other = (t >= off) ? tsum[t - off] : 0;
    __syncthreads();
    tsum[t] += other;
    __syncthreads();
  }
  int run = (t > 0) ? tsum[t - 1] : 0;  // exclusive prefix for this thread
  for (int i = beg; i < end; ++i) {
    offsets[i] = run;
    cursor[i] = run;
    run += counts[i];
  }
  if (t == 1023) offsets[N_NODES] = tsum[1023];
}

// ---------------- Phase 2c: bucket-scatter edges into dst order -------------
__global__ __launch_bounds__(256) void scatter_sort(
    const int* __restrict__ esrc, const int* __restrict__ edst,
    const float* __restrict__ eval, int* __restrict__ cursor,
    int* __restrict__ ssrc, float* __restrict__ sval, int n_edges) {
  int i = (blockIdx.x * 256 + threadIdx.x) * 4;
  if (i + 3 < n_edges) {
    const int4   s = *(const int4*)(esrc + i);
    const int4   d = *(const int4*)(edst + i);
    const float4 v = *(const float4*)(eval + i);
    int p;
    p = atomicAdd(&cursor[d.x], 1); ssrc[p] = s.x; sval[p] = v.x;
    p = atomicAdd(&cursor[d.y], 1); ssrc[p] = s.y; sval[p] = v.y;
    p = atomicAdd(&cursor[d.z], 1); ssrc[p] = s.z; sval[p] = v.z;
    p = atomicAdd(&cursor[d.w], 1); ssrc[p] = s.w; sval[p] = v.w;
  } else {
    for (; i < n_edges; ++i) {
      const int p = atomicAdd(&cursor[edst[i]], 1);
      ssrc[p] = esrc[i]; sval[p] = eval[i];
    }
  }
}

// ---------------- Phase 3: per-dst wave reduction + bias + relu -------------
// One 64-lane wave per dst. lane = feature. Edge (src,val) read coalesced by
// lanes then broadcast via shfl; gather of support row is one 256B coalesced
// load per edge. Single streamed write per output row (no atomics).
__global__ __launch_bounds__(256) void aggregate(
    const float* __restrict__ support, const int* __restrict__ offsets,
    const int* __restrict__ ssrc, const float* __restrict__ sval,
    const float* __restrict__ bias, float* __restrict__ out) {
  const int tid = threadIdx.x;
  const int f = tid & 63;
  const int dst = blockIdx.x * 4 + (tid >> 6);
  if (dst >= N_NODES) return;
  const int beg = offsets[dst];
  const int end = offsets[dst + 1];
  float acc = 0.f;
  for (int base = beg; base < end; base += 64) {
    const int n = min(64, end - base);
    int s = 0; float v = 0.f;
    if (f < n) { s = ssrc[base + f]; v = sval[base + f]; }
#pragma unroll 4
    for (int j = 0; j < n; ++j) {
      const int   sj = __shfl(s, j);
      const float vj = __shfl(v, j);
      acc += support[(size_t)sj * D_OUT + f] * vj;
    }
  }
  out[(size_t)dst * D_OUT + f] = fmaxf(acc + bias[f], 0.f);
}

// ---------------- Fallback (ws too small): atomic scatter -------------------
#define EPG 8
__global__ __launch_bounds__(256) void scatter_edges(
    const float* __restrict__ support, const int* __restrict__ esrc,
    const int* __restrict__ edst, const float* __restrict__ eval,
    float* __restrict__ out, int n_edges) {
  const int tid = threadIdx.x;
  const int f = tid & 63;
  const int grp = blockIdx.x * 4 + (tid >> 6);
  const int e0 = grp * EPG;
  int s[EPG], d[EPG];
  float v[EPG];
#pragma unroll
  for (int i = 0; i < EPG; ++i) {
    const int e = e0 + i;
    if (e < n_edges) { s[i] = esrc[e]; d[i] = edst[e]; v[i] = eval[e]; }
    else             { s[i] = 0; d[i] = 0; v[i] = 0.f; }
  }
  float m[EPG];
#pragma unroll
  for (int i = 0; i < EPG; ++i)
    m[i] = support[(size_t)s[i] * D_OUT + f] * v[i];
#pragma unroll
  for (int i = 0; i < EPG; ++i)
    if (e0 + i < n_edges) atomicAdd(&out[(size_t)d[i] * D_OUT + f], m[i]);
}

__global__ __launch_bounds__(256) void bias_relu(
    float* __restrict__ out, const float* __restrict__ b) {
  const int i = blockIdx.x * 256 + threadIdx.x;
  float4* o4 = (float4*)out;
  float4 v = o4[i];
  const int fb = (i * 4) & 63;
  const float4 bb = *(const float4*)&b[fb];
  v.x = fmaxf(v.x + bb.x, 0.f);
  v.y = fmaxf(v.y + bb.y, 0.f);
  v.z = fmaxf(v.z + bb.z, 0.f);
  v.w = fmaxf(v.w + bb.w, 0.f);
  o4[i] = v;
}

extern "C" void kernel_launch(void* const* d_in, const int* in_sizes, int n_in,
                              void* d_out, int out_size, void* d_ws, size_t ws_size,
                              hipStream_t stream) {
  const float* x    = (const float*)d_in[0];
  const int*   esrc = (const int*)  d_in[1];
  const int*   edst = (const int*)  d_in[2];
  const float* eval = (const float*)d_in[3];
  const float* W    = (const float*)d_in[4];
  const float* b    = (const float*)d_in[5];
  float* out = (float*)d_out;
  const int n_edges = in_sizes[1];

  // ---- workspace layout (256B aligned) ----
  size_t off = 0;
  auto alloc = [&](size_t bytes) {
    size_t o = off;
    off = (off + bytes + 255) & ~(size_t)255;
    return o;
  };
  char* ws = (char*)d_ws;
  const size_t sup_o  = alloc((size_t)N_NODES * D_OUT * sizeof(float));
  const size_t cnt_o  = alloc((size_t)N_NODES * sizeof(int));
  const size_t cur_o  = alloc((size_t)N_NODES * sizeof(int));
  const size_t offs_o = alloc(((size_t)N_NODES + 1) * sizeof(int));
  const size_t ssrc_o = alloc((size_t)N_EDGES_MAX * sizeof(int));
  const size_t sval_o = alloc((size_t)N_EDGES_MAX * sizeof(float));
  const size_t req = off;

  float* support = (float*)(ws + sup_o);

  gemm_xw<<<N_NODES / NPB, 256, 0, stream>>>(x, W, support);

  if (ws_size >= req && n_edges <= N_EDGES_MAX) {
    int*   counts  = (int*)  (ws + cnt_o);
    int*   cursor  = (int*)  (ws + cur_o);
    int*   offsets = (int*)  (ws + offs_o);
    int*   ssrc    = (int*)  (ws + ssrc_o);
    float* sval    = (float*)(ws + sval_o);

    hipMemsetAsync(counts, 0, (size_t)N_NODES * sizeof(int), stream);

    const int vblocks = (n_edges + 256 * 4 - 1) / (256 * 4);
    hist_dst<<<vblocks, 256, 0, stream>>>(edst, counts, n_edges);
    scan_offsets<<<1, 1024, 0, stream>>>(counts, offsets, cursor);
    scatter_sort<<<vblocks, 256, 0, stream>>>(esrc, edst, eval, cursor,
                                              ssrc, sval, n_edges);
    aggregate<<<(N_NODES + 3) / 4, 256, 0, stream>>>(support, offsets,
                                                     ssrc, sval, b, out);
  } else {
    // fallback: atomic scatter into zeroed out, then bias+relu
    hipMemsetAsync(d_out, 0, (size_t)N_NODES * D_OUT * sizeof(float), stream);
    const int groups = (n_edges + EPG - 1) / EPG;
    scatter_edges<<<(groups + 3) / 4, 256, 0, stream>>>(support, esrc, edst,
                                                        eval, out, n_edges);
    bias_relu<<<N_NODES * D_OUT / 4 / 256, 256, 0, stream>>>(out, b);
  }
}

// Round 4
// 246.692 us; speedup vs baseline: 1.4091x; 1.4091x over previous
//
#include <hip/hip_runtime.h>

#define N_NODES 50000
#define N_EDGES_MAX 800000
#define D_IN    128
#define D_OUT   64

// ---------------- Phase 1: support = x @ W  (f32 vector FMA) ----------------
#define NPB 16

__global__ __launch_bounds__(256) void gemm_xw(
    const float* __restrict__ x, const float* __restrict__ W,
    float* __restrict__ support) {
  __shared__ float Wlds[D_IN][D_OUT];   // 32 KiB
  __shared__ float xlds[NPB][D_IN];     //  8 KiB
  const int tid = threadIdx.x;
  const int node0 = blockIdx.x * NPB;

  const float4* W4 = (const float4*)W;
  float4* Wl4 = (float4*)Wlds;
#pragma unroll
  for (int i = 0; i < (D_IN * D_OUT / 4) / 256; ++i)
    Wl4[tid + i * 256] = W4[tid + i * 256];

  const float4* x4 = (const float4*)(x + (size_t)node0 * D_IN);
  float4* xl4 = (float4*)xlds;
#pragma unroll
  for (int i = 0; i < (NPB * D_IN / 4) / 256; ++i)
    xl4[tid + i * 256] = x4[tid + i * 256];

  __syncthreads();

  const int f = tid & 63;
  const int g = tid >> 6;
  float acc0 = 0.f, acc1 = 0.f, acc2 = 0.f, acc3 = 0.f;

#pragma unroll
  for (int k = 0; k < D_IN; k += 4) {
    const float w0 = Wlds[k + 0][f];
    const float w1 = Wlds[k + 1][f];
    const float w2 = Wlds[k + 2][f];
    const float w3 = Wlds[k + 3][f];
    const float4 xa = *(const float4*)&xlds[g * 4 + 0][k];
    const float4 xb = *(const float4*)&xlds[g * 4 + 1][k];
    const float4 xc = *(const float4*)&xlds[g * 4 + 2][k];
    const float4 xd = *(const float4*)&xlds[g * 4 + 3][k];
    acc0 += xa.x * w0 + xa.y * w1 + xa.z * w2 + xa.w * w3;
    acc1 += xb.x * w0 + xb.y * w1 + xb.z * w2 + xb.w * w3;
    acc2 += xc.x * w0 + xc.y * w1 + xc.z * w2 + xc.w * w3;
    acc3 += xd.x * w0 + xd.y * w1 + xd.z * w2 + xd.w * w3;
  }

  const int nbase = node0 + g * 4;
  support[(size_t)(nbase + 0) * D_OUT + f] = acc0;
  support[(size_t)(nbase + 1) * D_OUT + f] = acc1;
  support[(size_t)(nbase + 2) * D_OUT + f] = acc2;
  support[(size_t)(nbase + 3) * D_OUT + f] = acc3;
}

// ---------------- Phase 2a: histogram of edge_dst ---------------------------
__global__ __launch_bounds__(256) void hist_dst(
    const int* __restrict__ edst, int* __restrict__ counts, int n_edges) {
  int i = (blockIdx.x * 256 + threadIdx.x) * 4;
  if (i + 3 < n_edges) {
    const int4 d = *(const int4*)(edst + i);
    atomicAdd(&counts[d.x], 1);
    atomicAdd(&counts[d.y], 1);
    atomicAdd(&counts[d.z], 1);
    atomicAdd(&counts[d.w], 1);
  } else {
    for (; i < n_edges; ++i) atomicAdd(&counts[edst[i]], 1);
  }
}

// ---------------- Phase 2b: hierarchical exclusive scan ---------------------
// scan1: 49 blocks x 256 thr, 4 items/thr (1024/block). Local exclusive scan
//        written to offsets[]; block total to bsum[blk].
#define SCAN_ITEMS 1024
#define SCAN_NB ((N_NODES + SCAN_ITEMS - 1) / SCAN_ITEMS)  // 49

__global__ __launch_bounds__(256) void scan1(
    const int* __restrict__ counts, int* __restrict__ offsets,
    int* __restrict__ bsum) {
  __shared__ int tsum[256];
  const int t = threadIdx.x;
  const int i0 = blockIdx.x * SCAN_ITEMS + t * 4;
  int c0 = 0, c1 = 0, c2 = 0, c3 = 0;
  if (i0 + 3 < N_NODES) {
    const int4 c = *(const int4*)(counts + i0);
    c0 = c.x; c1 = c.y; c2 = c.z; c3 = c.w;
  } else if (i0 < N_NODES) {
    c0 = counts[i0];
    if (i0 + 1 < N_NODES) c1 = counts[i0 + 1];
    if (i0 + 2 < N_NODES) c2 = counts[i0 + 2];
  }
  const int s = c0 + c1 + c2 + c3;
  tsum[t] = s;
  __syncthreads();
  // Hillis-Steele inclusive scan over 256 thread sums
  for (int off = 1; off < 256; off <<= 1) {
    const int other = (t >= off) ? tsum[t - off] : 0;
    __syncthreads();
    tsum[t] += other;
    __syncthreads();
  }
  int pref = tsum[t] - s;  // exclusive prefix for this thread within block
  if (i0 < N_NODES) {
    offsets[i0] = pref;
    if (i0 + 1 < N_NODES) offsets[i0 + 1] = pref + c0;
    if (i0 + 2 < N_NODES) offsets[i0 + 2] = pref + c0 + c1;
    if (i0 + 3 < N_NODES) offsets[i0 + 3] = pref + c0 + c1 + c2;
  }
  if (t == 255) bsum[blockIdx.x] = tsum[255];
}

// scan2: single wave scans SCAN_NB block sums -> exclusive prefixes
__global__ __launch_bounds__(64) void scan2(
    const int* __restrict__ bsum, int* __restrict__ bpref) {
  const int t = threadIdx.x;
  int v = (t < SCAN_NB) ? bsum[t] : 0;
  const int orig = v;
  for (int off = 1; off < 64; off <<= 1) {
    const int n = __shfl_up(v, off);
    if (t >= off) v += n;
  }
  if (t < SCAN_NB) bpref[t] = v - orig;  // exclusive
}

// scan3: add block prefix, emit offsets + cursor; set offsets[N_NODES]
__global__ __launch_bounds__(256) void scan3(
    int* __restrict__ offsets, int* __restrict__ cursor,
    const int* __restrict__ bpref, int n_edges) {
  const int t = threadIdx.x;
  const int i0 = blockIdx.x * SCAN_ITEMS + t * 4;
  const int bp = bpref[blockIdx.x];
  if (i0 + 3 < N_NODES) {
    int4 o = *(const int4*)(offsets + i0);
    o.x += bp; o.y += bp; o.z += bp; o.w += bp;
    *(int4*)(offsets + i0) = o;
    *(int4*)(cursor + i0) = o;
  } else {
    for (int i = i0; i < N_NODES; ++i) {
      if (i >= i0 + 4) break;
      const int o = offsets[i] + bp;
      offsets[i] = o;
      cursor[i] = o;
    }
  }
  if (blockIdx.x == 0 && t == 0) offsets[N_NODES] = n_edges;
}

// ---------------- Phase 2c: bucket-scatter edges into dst order -------------
// (src, val) packed to one int2 -> single random 8B write per edge.
__global__ __launch_bounds__(256) void scatter_sort(
    const int* __restrict__ esrc, const int* __restrict__ edst,
    const float* __restrict__ eval, int* __restrict__ cursor,
    int2* __restrict__ svp, int n_edges) {
  int i = (blockIdx.x * 256 + threadIdx.x) * 4;
  if (i + 3 < n_edges) {
    const int4   s = *(const int4*)(esrc + i);
    const int4   d = *(const int4*)(edst + i);
    const float4 v = *(const float4*)(eval + i);
    int p;
    p = atomicAdd(&cursor[d.x], 1); svp[p] = make_int2(s.x, __float_as_int(v.x));
    p = atomicAdd(&cursor[d.y], 1); svp[p] = make_int2(s.y, __float_as_int(v.y));
    p = atomicAdd(&cursor[d.z], 1); svp[p] = make_int2(s.z, __float_as_int(v.z));
    p = atomicAdd(&cursor[d.w], 1); svp[p] = make_int2(s.w, __float_as_int(v.w));
  } else {
    for (; i < n_edges; ++i) {
      const int p = atomicAdd(&cursor[edst[i]], 1);
      svp[p] = make_int2(esrc[i], __float_as_int(eval[i]));
    }
  }
}

// ---------------- Phase 3: per-dst wave reduction + bias + relu -------------
__global__ __launch_bounds__(256) void aggregate(
    const float* __restrict__ support, const int* __restrict__ offsets,
    const int2* __restrict__ svp, const float* __restrict__ bias,
    float* __restrict__ out) {
  const int tid = threadIdx.x;
  const int f = tid & 63;
  const int dst = blockIdx.x * 4 + (tid >> 6);
  if (dst >= N_NODES) return;
  const int beg = offsets[dst];
  const int end = offsets[dst + 1];
  float acc = 0.f;
  for (int base = beg; base < end; base += 64) {
    const int n = min(64, end - base);
    int s = 0; float v = 0.f;
    if (f < n) {
      const int2 sv = svp[base + f];
      s = sv.x; v = __int_as_float(sv.y);
    }
#pragma unroll 4
    for (int j = 0; j < n; ++j) {
      const int   sj = __shfl(s, j);
      const float vj = __shfl(v, j);
      acc += support[(size_t)sj * D_OUT + f] * vj;
    }
  }
  out[(size_t)dst * D_OUT + f] = fmaxf(acc + bias[f], 0.f);
}

// ---------------- Fallback (ws too small): atomic scatter -------------------
#define EPG 8
__global__ __launch_bounds__(256) void scatter_edges(
    const float* __restrict__ support, const int* __restrict__ esrc,
    const int* __restrict__ edst, const float* __restrict__ eval,
    float* __restrict__ out, int n_edges) {
  const int tid = threadIdx.x;
  const int f = tid & 63;
  const int grp = blockIdx.x * 4 + (tid >> 6);
  const int e0 = grp * EPG;
  int s[EPG], d[EPG];
  float v[EPG];
#pragma unroll
  for (int i = 0; i < EPG; ++i) {
    const int e = e0 + i;
    if (e < n_edges) { s[i] = esrc[e]; d[i] = edst[e]; v[i] = eval[e]; }
    else             { s[i] = 0; d[i] = 0; v[i] = 0.f; }
  }
  float m[EPG];
#pragma unroll
  for (int i = 0; i < EPG; ++i)
    m[i] = support[(size_t)s[i] * D_OUT + f] * v[i];
#pragma unroll
  for (int i = 0; i < EPG; ++i)
    if (e0 + i < n_edges) atomicAdd(&out[(size_t)d[i] * D_OUT + f], m[i]);
}

__global__ __launch_bounds__(256) void bias_relu(
    float* __restrict__ out, const float* __restrict__ b) {
  const int i = blockIdx.x * 256 + threadIdx.x;
  float4* o4 = (float4*)out;
  float4 v = o4[i];
  const int fb = (i * 4) & 63;
  const float4 bb = *(const float4*)&b[fb];
  v.x = fmaxf(v.x + bb.x, 0.f);
  v.y = fmaxf(v.y + bb.y, 0.f);
  v.z = fmaxf(v.z + bb.z, 0.f);
  v.w = fmaxf(v.w + bb.w, 0.f);
  o4[i] = v;
}

extern "C" void kernel_launch(void* const* d_in, const int* in_sizes, int n_in,
                              void* d_out, int out_size, void* d_ws, size_t ws_size,
                              hipStream_t stream) {
  const float* x    = (const float*)d_in[0];
  const int*   esrc = (const int*)  d_in[1];
  const int*   edst = (const int*)  d_in[2];
  const float* eval = (const float*)d_in[3];
  const float* W    = (const float*)d_in[4];
  const float* b    = (const float*)d_in[5];
  float* out = (float*)d_out;
  const int n_edges = in_sizes[1];

  // ---- workspace layout (256B aligned) ----
  size_t off = 0;
  auto alloc = [&](size_t bytes) {
    size_t o = off;
    off = (off + bytes + 255) & ~(size_t)255;
    return o;
  };
  char* ws = (char*)d_ws;
  const size_t sup_o  = alloc((size_t)N_NODES * D_OUT * sizeof(float));
  const size_t cnt_o  = alloc((size_t)N_NODES * sizeof(int));
  const size_t cur_o  = alloc((size_t)N_NODES * sizeof(int));
  const size_t offs_o = alloc(((size_t)N_NODES + 1) * sizeof(int));
  const size_t bsum_o = alloc((size_t)SCAN_NB * sizeof(int));
  const size_t bprf_o = alloc((size_t)SCAN_NB * sizeof(int));
  const size_t svp_o  = alloc((size_t)N_EDGES_MAX * sizeof(int2));
  const size_t req = off;

  float* support = (float*)(ws + sup_o);

  gemm_xw<<<N_NODES / NPB, 256, 0, stream>>>(x, W, support);

  if (ws_size >= req && n_edges <= N_EDGES_MAX) {
    int*  counts  = (int*) (ws + cnt_o);
    int*  cursor  = (int*) (ws + cur_o);
    int*  offsets = (int*) (ws + offs_o);
    int*  bsum    = (int*) (ws + bsum_o);
    int*  bpref   = (int*) (ws + bprf_o);
    int2* svp     = (int2*)(ws + svp_o);

    hipMemsetAsync(counts, 0, (size_t)N_NODES * sizeof(int), stream);

    const int vblocks = (n_edges + 256 * 4 - 1) / (256 * 4);
    hist_dst<<<vblocks, 256, 0, stream>>>(edst, counts, n_edges);
    scan1<<<SCAN_NB, 256, 0, stream>>>(counts, offsets, bsum);
    scan2<<<1, 64, 0, stream>>>(bsum, bpref);
    scan3<<<SCAN_NB, 256, 0, stream>>>(offsets, cursor, bpref, n_edges);
    scatter_sort<<<vblocks, 256, 0, stream>>>(esrc, edst, eval, cursor,
                                              svp, n_edges);
    aggregate<<<(N_NODES + 3) / 4, 256, 0, stream>>>(support, offsets,
                                                     svp, b, out);
  } else {
    // fallback: atomic scatter into zeroed out, then bias+relu
    hipMemsetAsync(d_out, 0, (size_t)N_NODES * D_OUT * sizeof(float), stream);
    const int groups = (n_edges + EPG - 1) / EPG;
    scatter_edges<<<(groups + 3) / 4, 256, 0, stream>>>(support, esrc, edst,
                                                        eval, out, n_edges);
    bias_relu<<<N_NODES * D_OUT / 4 / 256, 256, 0, stream>>>(out, b);
  }
}